// Round 14
// baseline (243.513 us; speedup 1.0000x reference)
//
#include <hip/hip_runtime.h>
#include <hip/hip_bf16.h>

#define N_NODES 50000
#define N_PAD 50048
#define N_EDGES 500000
#define IN_CH 128
#define OUT_CH 128
#define NEG_SLOPE 0.2f
#define EPS_F 1e-16f

typedef __attribute__((ext_vector_type(8))) short bf16x8;
typedef __attribute__((ext_vector_type(4))) float f32x4;

__device__ __forceinline__ unsigned short bf16_rne(float f) {
    unsigned int u = __float_as_uint(f);
    u += 0x7FFFu + ((u >> 16) & 1u);
    return (unsigned short)(u >> 16);
}
__device__ __forceinline__ float bf16_to_f32(unsigned short h) {
    return __uint_as_float(((unsigned int)h) << 16);
}

// swizzled element offset within [n][128] layout (row-XOR folded into global)
#define XSWZ(n, k) ((size_t)(n) * 128 + ((k) ^ (((n) & 7) << 3)))
// LDS swizzle for a 128-row tile (row = local row)
#define LSWZ(row, col) ((row) * 128 + ((col) ^ (((row) & 7) << 3)))

// direct global->LDS 16B copy (dest = wave-uniform base + lane*16)
__device__ __forceinline__ void gload16(const unsigned short* g, unsigned short* l) {
    __builtin_amdgcn_global_load_lds(
        (const __attribute__((address_space(1))) unsigned int*)g,
        (__attribute__((address_space(3))) unsigned int*)l, 16, 0, 0);
}

// ---------------------------------------------------------------------------
// Kernel 0: prep.
//  (a) x fp32 -> xhi/xlo bf16, PRE-SWIZZLED [50048][128] (pad rows = 0)
//  (b) Bt_hi/Bt_lo [384][128] linear (rows 0..255 = W0^T|W1^T, 256.. = root_w)
// ---------------------------------------------------------------------------
__global__ __launch_bounds__(256) void prep_kernel(
    const float* __restrict__ x, const float* __restrict__ weight,
    const float* __restrict__ root_w,
    unsigned short* __restrict__ xhi, unsigned short* __restrict__ xlo,
    unsigned short* __restrict__ bt_hi, unsigned short* __restrict__ bt_lo)
{
    const int gid = blockIdx.x * 256 + threadIdx.x;
    const int gsz = gridDim.x * 256;

    // (a) 50048*32 float4 units
    const float4* xg = (const float4*)x;
    for (int i = gid; i < N_PAD * 32; i += gsz) {
        int n = i >> 5, c4 = i & 31;
        float4 v = make_float4(0.f, 0.f, 0.f, 0.f);
        if (n < N_NODES) v = xg[(size_t)n * 32 + c4];
        unsigned short h0 = bf16_rne(v.x), h1 = bf16_rne(v.y),
                       h2 = bf16_rne(v.z), h3 = bf16_rne(v.w);
        ushort4 hh = make_ushort4(h0, h1, h2, h3);
        ushort4 ll = make_ushort4(bf16_rne(v.x - bf16_to_f32(h0)),
                                  bf16_rne(v.y - bf16_to_f32(h1)),
                                  bf16_rne(v.z - bf16_to_f32(h2)),
                                  bf16_rne(v.w - bf16_to_f32(h3)));
        size_t off = XSWZ(n, c4 * 4);
        *(ushort4*)&xhi[off] = hh;
        *(ushort4*)&xlo[off] = ll;
    }

    // (b) 384*128 scalars
    for (int i = gid; i < 384 * 128; i += gsz) {
        int n = i >> 7, k = i & 127;
        float v;
        if (n < 256) {
            int t = n >> 7, o = n & 127;
            v = weight[(size_t)t * 16384 + (size_t)k * 128 + o];
        } else {
            v = root_w[(size_t)(n - 256) * 128 + k];
        }
        unsigned short h = bf16_rne(v);
        bt_hi[i] = h;
        bt_lo[i] = bf16_rne(v - bf16_to_f32(h));
    }
}

// ---------------------------------------------------------------------------
// Kernel 1: bf16x3 split-MFMA GEMM + fused sL/sR epilogue.
//   A staged via global_load_lds (pre-swizzled source, zero VALU);
//   B frags from global (L2-hot). 4 waves * 64x64; 3 MFMA passes.
//   c<2 epilogue: sL[n][c] = hall_row . att[c][:128], sR = . att[c][128:]
// ---------------------------------------------------------------------------
#define MBLK 391

__global__ __launch_bounds__(256, 2) void mfma_gemm_kernel(
    const unsigned short* __restrict__ xhi,
    const unsigned short* __restrict__ xlo,
    const unsigned short* __restrict__ bt_hi,
    const unsigned short* __restrict__ bt_lo,
    const float* __restrict__ att, const float* __restrict__ root_b,
    float* __restrict__ hall, float* __restrict__ out,
    float* __restrict__ sL, float* __restrict__ sR)
{
    __shared__ unsigned short Ah[128 * 128];
    __shared__ unsigned short Al[128 * 128];
    __shared__ float sLds[128][2];

    const int tid = threadIdx.x;
    const int lane = tid & 63;
    const int w = tid >> 6;
    const int bid = blockIdx.x;
    const int c = bid / MBLK;            // output chunk 0..2
    const int m0 = (bid - c * MBLK) * 128;

    if (tid < 128) { sLds[tid][0] = 0.f; sLds[tid][1] = 0.f; }

    // --- stage A via global_load_lds: 8 passes x 2 matrices, 16B/lane
    {
        const unsigned short* srch = xhi + (size_t)m0 * 128;
        const unsigned short* srcl = xlo + (size_t)m0 * 128;
        #pragma unroll
        for (int it = 0; it < 8; ++it) {
            int base = it * 2048 + w * 512;      // wave-uniform elem offset
            gload16(srch + base + lane * 8, &Ah[base]);
            gload16(srcl + base + lane * 8, &Al[base]);
        }
    }
    __syncthreads();

    // --- compute: 4 waves, each 64x64 tile; B frags from global (L2)
    const int mh = (w >> 1) * 64;
    const int nh = (w & 1) * 64;
    const int lr = lane & 15;
    const int lk = (lane >> 4) * 8;

    const unsigned short* bh_base =
        bt_hi + ((size_t)(c * 128 + nh + lr)) * 128 + lk;
    const unsigned short* bl_base =
        bt_lo + ((size_t)(c * 128 + nh + lr)) * 128 + lk;

    f32x4 acc[4][4];
    #pragma unroll
    for (int mi = 0; mi < 4; ++mi)
        #pragma unroll
        for (int ni = 0; ni < 4; ++ni)
            acc[mi][ni] = (f32x4){0.f, 0.f, 0.f, 0.f};

    #pragma unroll
    for (int ks = 0; ks < 4; ++ks) {
        const int ko = ks * 32 + lk;
        bf16x8 bh[4], bl[4];
        #pragma unroll
        for (int ni = 0; ni < 4; ++ni) {
            bh[ni] = *(const bf16x8*)(bh_base + ni * 2048 + ks * 32);
            bl[ni] = *(const bf16x8*)(bl_base + ni * 2048 + ks * 32);
        }
        bf16x8 ah[4], al[4];
        #pragma unroll
        for (int mi = 0; mi < 4; ++mi) {
            int off = LSWZ(mh + mi * 16 + lr, ko);
            ah[mi] = *(const bf16x8*)&Ah[off];
            al[mi] = *(const bf16x8*)&Al[off];
        }
        #pragma unroll
        for (int mi = 0; mi < 4; ++mi)
            #pragma unroll
            for (int ni = 0; ni < 4; ++ni) {
                acc[mi][ni] = __builtin_amdgcn_mfma_f32_16x16x32_bf16(
                    ah[mi], bh[ni], acc[mi][ni], 0, 0, 0);
                acc[mi][ni] = __builtin_amdgcn_mfma_f32_16x16x32_bf16(
                    ah[mi], bl[ni], acc[mi][ni], 0, 0, 0);
                acc[mi][ni] = __builtin_amdgcn_mfma_f32_16x16x32_bf16(
                    al[mi], bh[ni], acc[mi][ni], 0, 0, 0);
            }
    }

    // --- write C (layout: col = lane&15, row = (lane>>4)*4 + reg)
    const int crow = (lane >> 4) * 4;
    const int ccol = lane & 15;
    if (c < 2) {
        #pragma unroll
        for (int mi = 0; mi < 4; ++mi)
            #pragma unroll
            for (int j = 0; j < 4; ++j) {
                int gm = m0 + mh + mi * 16 + crow + j;
                if (gm < N_NODES) {
                    #pragma unroll
                    for (int ni = 0; ni < 4; ++ni) {
                        int n = nh + ni * 16 + ccol;
                        hall[((size_t)gm * 2 + c) * 128 + n] = acc[mi][ni][j];
                    }
                }
            }
        // --- fused sL/sR: per-row dot with att[c][:128] / att[c][128:]
        float attLv[4], attRv[4];
        #pragma unroll
        for (int ni = 0; ni < 4; ++ni) {
            attLv[ni] = att[c * 256 + nh + ni * 16 + ccol];
            attRv[ni] = att[c * 256 + 128 + nh + ni * 16 + ccol];
        }
        #pragma unroll
        for (int mi = 0; mi < 4; ++mi)
            #pragma unroll
            for (int j = 0; j < 4; ++j) {
                float pL = acc[mi][0][j] * attLv[0] + acc[mi][1][j] * attLv[1]
                         + acc[mi][2][j] * attLv[2] + acc[mi][3][j] * attLv[3];
                float pR = acc[mi][0][j] * attRv[0] + acc[mi][1][j] * attRv[1]
                         + acc[mi][2][j] * attRv[2] + acc[mi][3][j] * attRv[3];
                #pragma unroll
                for (int off = 1; off < 16; off <<= 1) {
                    pL += __shfl_xor(pL, off);
                    pR += __shfl_xor(pR, off);
                }
                if (ccol == 0) {
                    int rl = mh + mi * 16 + crow + j;
                    atomicAdd(&sLds[rl][0], pL);
                    atomicAdd(&sLds[rl][1], pR);
                }
            }
        __syncthreads();
        if (tid < 128) {
            sL[(size_t)(m0 + tid) * 2 + c] = sLds[tid][0];
            sR[(size_t)(m0 + tid) * 2 + c] = sLds[tid][1];
        }
    } else {
        float rbv[4];
        #pragma unroll
        for (int ni = 0; ni < 4; ++ni) rbv[ni] = root_b[nh + ni * 16 + ccol];
        #pragma unroll
        for (int mi = 0; mi < 4; ++mi)
            #pragma unroll
            for (int j = 0; j < 4; ++j) {
                int gm = m0 + mh + mi * 16 + crow + j;
                if (gm < N_NODES) {
                    #pragma unroll
                    for (int ni = 0; ni < 4; ++ni) {
                        int n = nh + ni * 16 + ccol;
                        out[(size_t)gm * 128 + n] = acc[mi][ni][j] + rbv[ni];
                    }
                }
            }
    }
}

// ---------------------------------------------------------------------------
// CSR build: histogram -> block scan -> fused prefix+add -> scatter
// ---------------------------------------------------------------------------
__global__ __launch_bounds__(256) void hist_kernel(
    const int* __restrict__ ei, int* __restrict__ deg)
{
    int i = blockIdx.x * 256 + threadIdx.x;
    if (i < N_EDGES) atomicAdd(&deg[ei[N_EDGES + i]], 1);
}

__global__ __launch_bounds__(256) void scan1_kernel(
    const int* __restrict__ deg, int* __restrict__ rp, int* __restrict__ bsum)
{
    __shared__ int s[256];
    int i = blockIdx.x * 256 + threadIdx.x;
    int v = (i < N_NODES) ? deg[i] : 0;
    s[threadIdx.x] = v;
    __syncthreads();
    #pragma unroll
    for (int off = 1; off < 256; off <<= 1) {
        int t = (threadIdx.x >= off) ? s[threadIdx.x - off] : 0;
        __syncthreads();
        s[threadIdx.x] += t;
        __syncthreads();
    }
    if (i < N_NODES) rp[i + 1] = s[threadIdx.x];
    if (threadIdx.x == 255) bsum[blockIdx.x] = s[255];
    if (i == 0) rp[0] = 0;
}

// each block computes its own exclusive prefix of bsum, adds to its rp slice
__global__ __launch_bounds__(256) void scan23_kernel(
    int* __restrict__ rp, const int* __restrict__ bsum, int nb)
{
    __shared__ int bl[256];
    int tid = threadIdx.x;
    bl[tid] = (tid < nb && tid < (int)blockIdx.x) ? bsum[tid] : 0;
    __syncthreads();
    #pragma unroll
    for (int off = 128; off; off >>= 1) {
        if (tid < off) bl[tid] += bl[tid + off];
        __syncthreads();
    }
    int pre = bl[0];
    int i = blockIdx.x * 256 + tid;
    if (i < N_NODES) rp[i + 1] += pre;
}

__global__ __launch_bounds__(256) void csr_scatter_kernel(
    const int* __restrict__ ei, const int* __restrict__ etype,
    const int* __restrict__ rp, int* __restrict__ cursor, int* __restrict__ skey)
{
    int i = blockIdx.x * 256 + threadIdx.x;
    if (i >= N_EDGES) return;
    int dst = ei[N_EDGES + i];
    int pos = rp[dst] + atomicAdd(&cursor[dst], 1);
    skey[pos] = (ei[i] << 1) | (etype[i] & 1);
}

// ---------------------------------------------------------------------------
// node_agg v3: wave per node. Phase A: lanes-parallel scalar logits -> max.
// Phase B: half-wave per edge (float4 PV), 2x unrolled, no shuffle reduces.
// ---------------------------------------------------------------------------
__global__ __launch_bounds__(256) void node_agg_kernel(
    const int* __restrict__ rp, const int* __restrict__ skey,
    const float* __restrict__ hall,
    const float* __restrict__ sL, const float* __restrict__ sR,
    float* __restrict__ out)
{
    const int lane = threadIdx.x & 63;
    const int node = (blockIdx.x * 256 + threadIdx.x) >> 6;
    if (node >= N_NODES) return;
    const int r0 = rp[node], r1 = rp[node + 1];
    if (r0 == r1) return;                 // out keeps root contribution

    const float sR0 = sR[(size_t)node * 2 + 0];
    const float sR1 = sR[(size_t)node * 2 + 1];
    const float NINF = -__builtin_inff();

    // Phase A: segment max (lanes parallel over edges)
    float mloc = NINF;
    for (int j = r0 + lane; j < r1; j += 64) {
        int key = skey[j], t = key & 1;
        float e = sL[(size_t)(key >> 1) * 2 + t] + (t ? sR1 : sR0);
        e = (e > 0.f) ? e : NEG_SLOPE * e;
        mloc = fmaxf(mloc, e);
    }
    #pragma unroll
    for (int off = 32; off; off >>= 1) mloc = fmaxf(mloc, __shfl_xor(mloc, off));

    // Phase B: half-wave per edge, 2 edges per half per iteration
    const int sl = lane & 31;
    const int half = lane >> 5;
    float denom = 0.f;
    float4 acc = make_float4(0.f, 0.f, 0.f, 0.f);

    for (int j = r0 + half; j < r1; j += 4) {
        const int j2 = j + 2;
        const bool v2 = j2 < r1;
        const int k1 = skey[j];
        const int k2 = skey[v2 ? j2 : j];
        const int t1 = k1 & 1, t2 = k2 & 1;

        float e1 = sL[(size_t)(k1 >> 1) * 2 + t1] + (t1 ? sR1 : sR0);
        float e2 = sL[(size_t)(k2 >> 1) * 2 + t2] + (t2 ? sR1 : sR0);
        e1 = (e1 > 0.f) ? e1 : NEG_SLOPE * e1;
        e2 = (e2 > 0.f) ? e2 : NEG_SLOPE * e2;
        const float w1 = __expf(e1 - mloc);
        const float w2 = v2 ? __expf(e2 - mloc) : 0.f;

        const float4 h1 = *(const float4*)&hall[((size_t)(k1 >> 1) * 2 + t1) * 128 + sl * 4];
        const float4 h2 = *(const float4*)&hall[((size_t)(k2 >> 1) * 2 + t2) * 128 + sl * 4];

        denom += w1 + w2;
        acc.x += w1 * h1.x + w2 * h2.x;
        acc.y += w1 * h1.y + w2 * h2.y;
        acc.z += w1 * h1.z + w2 * h2.z;
        acc.w += w1 * h1.w + w2 * h2.w;
    }

    // merge the two halves (lane i <-> i+32 hold same channels)
    denom += __shfl_xor(denom, 32);
    acc.x += __shfl_xor(acc.x, 32);
    acc.y += __shfl_xor(acc.y, 32);
    acc.z += __shfl_xor(acc.z, 32);
    acc.w += __shfl_xor(acc.w, 32);

    if (half == 0) {
        const float inv = 1.f / (denom + EPS_F);
        float4* op = (float4*)&out[(size_t)node * 128 + sl * 4];
        float4 o = *op;
        o.x += acc.x * inv;
        o.y += acc.y * inv;
        o.z += acc.z * inv;
        o.w += acc.w * inv;
        *op = o;
    }
}

// ---------------------------------------------------------------------------
extern "C" void kernel_launch(void* const* d_in, const int* in_sizes, int n_in,
                              void* d_out, int out_size, void* d_ws, size_t ws_size,
                              hipStream_t stream) {
    const float* x      = (const float*)d_in[0];
    const int*   ei     = (const int*)d_in[1];
    const int*   etype  = (const int*)d_in[2];
    const float* weight = (const float*)d_in[3];
    const float* att    = (const float*)d_in[4];
    const float* root_w = (const float*)d_in[5];
    const float* root_b = (const float*)d_in[6];
    float* out = (float*)d_out;

    // ws layout (4-byte units, all sections 16B-aligned):
    float* ws = (float*)d_ws;
    float* hall   = ws;                                   // 50000*2*128
    float* sL     = hall + (size_t)N_NODES * 2 * 128;     // 50048*2
    float* sR     = sL + (size_t)N_PAD * 2;               // 50048*2
    int*   deg    = (int*)(sR + (size_t)N_PAD * 2);       // 50048
    int*   cursor = deg + N_PAD;                          // 50048
    int*   rp     = cursor + N_PAD;                       // 50056 (N+1 padded)
    int*   bsum   = rp + 50056;                           // 256
    int*   skey   = bsum + 256;                           // 500000
    unsigned short* xhi   = (unsigned short*)(skey + N_EDGES);  // 50048*128
    unsigned short* xlo   = xhi + (size_t)N_PAD * 128;
    unsigned short* bt_hi = xlo + (size_t)N_PAD * 128;          // 384*128
    unsigned short* bt_lo = bt_hi + 384 * 128;

    const int NB_E = (N_EDGES + 255) / 256;   // 1954
    const int NB_N = (N_NODES + 255) / 256;   // 196

    // zero deg + cursor (contiguous)
    hipMemsetAsync(deg, 0, sizeof(int) * (size_t)N_PAD * 2, stream);

    prep_kernel<<<2048, 256, 0, stream>>>(x, weight, root_w, xhi, xlo, bt_hi, bt_lo);

    mfma_gemm_kernel<<<3 * MBLK, 256, 0, stream>>>(
        xhi, xlo, bt_hi, bt_lo, att, root_b, hall, out, sL, sR);

    hist_kernel<<<NB_E, 256, 0, stream>>>(ei, deg);
    scan1_kernel<<<NB_N, 256, 0, stream>>>(deg, rp, bsum);
    scan23_kernel<<<NB_N, 256, 0, stream>>>(rp, bsum, NB_N);
    csr_scatter_kernel<<<NB_E, 256, 0, stream>>>(ei, etype, rp, cursor, skey);

    node_agg_kernel<<<(N_NODES + 3) / 4, 256, 0, stream>>>(
        rp, skey, hall, sL, sR, out);
}

// Round 15
// 233.689 us; speedup vs baseline: 1.0420x; 1.0420x over previous
//
#include <hip/hip_runtime.h>
#include <hip/hip_bf16.h>

#define N_NODES 50000
#define N_PAD 50048
#define N_EDGES 500000
#define NEG_SLOPE 0.2f
#define EPS_F 1e-16f

typedef __attribute__((ext_vector_type(8))) short bf16x8;
typedef __attribute__((ext_vector_type(4))) float f32x4;

__device__ __forceinline__ unsigned short bf16_rne(float f) {
    unsigned int u = __float_as_uint(f);
    u += 0x7FFFu + ((u >> 16) & 1u);
    return (unsigned short)(u >> 16);
}
__device__ __forceinline__ float bf16_to_f32(unsigned short h) {
    return __uint_as_float(((unsigned int)h) << 16);
}
__device__ __forceinline__ float4 bf4_to_f4(ushort4 u) {
    return make_float4(bf16_to_f32(u.x), bf16_to_f32(u.y),
                       bf16_to_f32(u.z), bf16_to_f32(u.w));
}

// swizzled element offset within [n][128] layout (row-XOR folded into global)
#define XSWZ(n, k) ((size_t)(n) * 128 + ((k) ^ (((n) & 7) << 3)))
// LDS swizzle (row = local row; m0 % 64 == 0 keeps row&7 consistent)
#define LSWZ(row, col) ((row) * 128 + ((col) ^ (((row) & 7) << 3)))

// direct global->LDS 16B copy (dest = wave-uniform base + lane*16)
__device__ __forceinline__ void gload16(const unsigned short* g, unsigned short* l) {
    __builtin_amdgcn_global_load_lds(
        (const __attribute__((address_space(1))) unsigned int*)g,
        (__attribute__((address_space(3))) unsigned int*)l, 16, 0, 0);
}

// ---------------------------------------------------------------------------
// Kernel 0: prep (fused).
//  (a) x fp32 -> xhi/xlo bf16, PRE-SWIZZLED [50048][128] (pad rows = 0)
//  (b) Bt_hi/Bt_lo [384][128] linear (0..255 = W0^T|W1^T, 256.. = root_w)
//  (c) dst-degree histogram
// ---------------------------------------------------------------------------
__global__ __launch_bounds__(256) void prep_kernel(
    const float* __restrict__ x, const float* __restrict__ weight,
    const float* __restrict__ root_w, const int* __restrict__ ei,
    unsigned short* __restrict__ xhi, unsigned short* __restrict__ xlo,
    unsigned short* __restrict__ bt_hi, unsigned short* __restrict__ bt_lo,
    int* __restrict__ deg)
{
    const int gid = blockIdx.x * 256 + threadIdx.x;
    const int gsz = gridDim.x * 256;

    // (a) 50048*32 float4 units
    const float4* xg = (const float4*)x;
    for (int i = gid; i < N_PAD * 32; i += gsz) {
        int n = i >> 5, c4 = i & 31;
        float4 v = make_float4(0.f, 0.f, 0.f, 0.f);
        if (n < N_NODES) v = xg[(size_t)n * 32 + c4];
        unsigned short h0 = bf16_rne(v.x), h1 = bf16_rne(v.y),
                       h2 = bf16_rne(v.z), h3 = bf16_rne(v.w);
        ushort4 hh = make_ushort4(h0, h1, h2, h3);
        ushort4 ll = make_ushort4(bf16_rne(v.x - bf16_to_f32(h0)),
                                  bf16_rne(v.y - bf16_to_f32(h1)),
                                  bf16_rne(v.z - bf16_to_f32(h2)),
                                  bf16_rne(v.w - bf16_to_f32(h3)));
        size_t off = XSWZ(n, c4 * 4);
        *(ushort4*)&xhi[off] = hh;
        *(ushort4*)&xlo[off] = ll;
    }

    // (b) 384*128 scalars
    for (int i = gid; i < 384 * 128; i += gsz) {
        int n = i >> 7, k = i & 127;
        float v;
        if (n < 256) {
            int t = n >> 7, o = n & 127;
            v = weight[(size_t)t * 16384 + (size_t)k * 128 + o];
        } else {
            v = root_w[(size_t)(n - 256) * 128 + k];
        }
        unsigned short h = bf16_rne(v);
        bt_hi[i] = h;
        bt_lo[i] = bf16_rne(v - bf16_to_f32(h));
    }

    // (c) histogram of dst
    for (int i = gid; i < N_EDGES; i += gsz)
        atomicAdd(&deg[ei[N_EDGES + i]], 1);
}

// ---------------------------------------------------------------------------
// Kernel 1: bf16x3 split-MFMA GEMM, 64-row tiles (33KB LDS -> 4 blocks/CU).
//   hall written as bf16. Fused sL/sR epilogue for c<2.
// ---------------------------------------------------------------------------
#define MBLK 782   // 50048 / 64

__global__ __launch_bounds__(256, 4) void mfma_gemm_kernel(
    const unsigned short* __restrict__ xhi,
    const unsigned short* __restrict__ xlo,
    const unsigned short* __restrict__ bt_hi,
    const unsigned short* __restrict__ bt_lo,
    const float* __restrict__ att, const float* __restrict__ root_b,
    unsigned short* __restrict__ hall, float* __restrict__ out,
    float* __restrict__ sL, float* __restrict__ sR)
{
    __shared__ unsigned short Ah[64 * 128];   // 16 KB
    __shared__ unsigned short Al[64 * 128];   // 16 KB
    __shared__ float sLds[64][2];

    const int tid = threadIdx.x;
    const int lane = tid & 63;
    const int w = tid >> 6;
    const int bid = blockIdx.x;
    const int c = bid / MBLK;            // output chunk 0..2
    const int m0 = (bid - c * MBLK) * 64;

    if (tid < 64) { sLds[tid][0] = 0.f; sLds[tid][1] = 0.f; }

    // --- stage A via global_load_lds: 4 passes x 2 matrices, 16B/lane
    {
        const unsigned short* srch = xhi + (size_t)m0 * 128;
        const unsigned short* srcl = xlo + (size_t)m0 * 128;
        #pragma unroll
        for (int it = 0; it < 4; ++it) {
            int base = it * 2048 + w * 512;      // wave-uniform elem offset
            gload16(srch + base + lane * 8, &Ah[base]);
            gload16(srcl + base + lane * 8, &Al[base]);
        }
    }
    __syncthreads();

    // --- compute: 4 waves, each 32x64 tile; B frags from global (L2)
    const int mh = (w >> 1) * 32;
    const int nh = (w & 1) * 64;
    const int lr = lane & 15;
    const int lk = (lane >> 4) * 8;

    const unsigned short* bh_base =
        bt_hi + ((size_t)(c * 128 + nh + lr)) * 128 + lk;
    const unsigned short* bl_base =
        bt_lo + ((size_t)(c * 128 + nh + lr)) * 128 + lk;

    f32x4 acc[2][4];
    #pragma unroll
    for (int mi = 0; mi < 2; ++mi)
        #pragma unroll
        for (int ni = 0; ni < 4; ++ni)
            acc[mi][ni] = (f32x4){0.f, 0.f, 0.f, 0.f};

    #pragma unroll
    for (int ks = 0; ks < 4; ++ks) {
        const int ko = ks * 32 + lk;
        bf16x8 bh[4], bl[4];
        #pragma unroll
        for (int ni = 0; ni < 4; ++ni) {
            bh[ni] = *(const bf16x8*)(bh_base + ni * 2048 + ks * 32);
            bl[ni] = *(const bf16x8*)(bl_base + ni * 2048 + ks * 32);
        }
        bf16x8 ah[2], al[2];
        #pragma unroll
        for (int mi = 0; mi < 2; ++mi) {
            int off = LSWZ(mh + mi * 16 + lr, ko);
            ah[mi] = *(const bf16x8*)&Ah[off];
            al[mi] = *(const bf16x8*)&Al[off];
        }
        #pragma unroll
        for (int mi = 0; mi < 2; ++mi)
            #pragma unroll
            for (int ni = 0; ni < 4; ++ni) {
                acc[mi][ni] = __builtin_amdgcn_mfma_f32_16x16x32_bf16(
                    ah[mi], bh[ni], acc[mi][ni], 0, 0, 0);
                acc[mi][ni] = __builtin_amdgcn_mfma_f32_16x16x32_bf16(
                    ah[mi], bl[ni], acc[mi][ni], 0, 0, 0);
                acc[mi][ni] = __builtin_amdgcn_mfma_f32_16x16x32_bf16(
                    al[mi], bh[ni], acc[mi][ni], 0, 0, 0);
            }
    }

    // --- write C (layout: col = lane&15, row = (lane>>4)*4 + reg)
    const int crow = (lane >> 4) * 4;
    const int ccol = lane & 15;
    if (c < 2) {
        #pragma unroll
        for (int mi = 0; mi < 2; ++mi)
            #pragma unroll
            for (int j = 0; j < 4; ++j) {
                int gm = m0 + mh + mi * 16 + crow + j;
                if (gm < N_NODES) {
                    #pragma unroll
                    for (int ni = 0; ni < 4; ++ni) {
                        int n = nh + ni * 16 + ccol;
                        hall[((size_t)gm * 2 + c) * 128 + n] = bf16_rne(acc[mi][ni][j]);
                    }
                }
            }
        // --- fused sL/sR: per-row dot with att[c][:128] / att[c][128:]
        float attLv[4], attRv[4];
        #pragma unroll
        for (int ni = 0; ni < 4; ++ni) {
            attLv[ni] = att[c * 256 + nh + ni * 16 + ccol];
            attRv[ni] = att[c * 256 + 128 + nh + ni * 16 + ccol];
        }
        #pragma unroll
        for (int mi = 0; mi < 2; ++mi)
            #pragma unroll
            for (int j = 0; j < 4; ++j) {
                float pL = acc[mi][0][j] * attLv[0] + acc[mi][1][j] * attLv[1]
                         + acc[mi][2][j] * attLv[2] + acc[mi][3][j] * attLv[3];
                float pR = acc[mi][0][j] * attRv[0] + acc[mi][1][j] * attRv[1]
                         + acc[mi][2][j] * attRv[2] + acc[mi][3][j] * attRv[3];
                #pragma unroll
                for (int off = 1; off < 16; off <<= 1) {
                    pL += __shfl_xor(pL, off);
                    pR += __shfl_xor(pR, off);
                }
                if (ccol == 0) {
                    int rl = mh + mi * 16 + crow + j;
                    atomicAdd(&sLds[rl][0], pL);
                    atomicAdd(&sLds[rl][1], pR);
                }
            }
        __syncthreads();
        if (tid < 64) {
            sL[(size_t)(m0 + tid) * 2 + c] = sLds[tid][0];
            sR[(size_t)(m0 + tid) * 2 + c] = sLds[tid][1];
        }
    } else {
        float rbv[4];
        #pragma unroll
        for (int ni = 0; ni < 4; ++ni) rbv[ni] = root_b[nh + ni * 16 + ccol];
        #pragma unroll
        for (int mi = 0; mi < 2; ++mi)
            #pragma unroll
            for (int j = 0; j < 4; ++j) {
                int gm = m0 + mh + mi * 16 + crow + j;
                if (gm < N_NODES) {
                    #pragma unroll
                    for (int ni = 0; ni < 4; ++ni) {
                        int n = nh + ni * 16 + ccol;
                        out[(size_t)gm * 128 + n] = acc[mi][ni][j] + rbv[ni];
                    }
                }
            }
    }
}

// ---------------------------------------------------------------------------
// CSR build: block scan -> fused prefix+add -> scatter
// ---------------------------------------------------------------------------
__global__ __launch_bounds__(256) void scan1_kernel(
    const int* __restrict__ deg, int* __restrict__ rp, int* __restrict__ bsum)
{
    __shared__ int s[256];
    int i = blockIdx.x * 256 + threadIdx.x;
    int v = (i < N_NODES) ? deg[i] : 0;
    s[threadIdx.x] = v;
    __syncthreads();
    #pragma unroll
    for (int off = 1; off < 256; off <<= 1) {
        int t = (threadIdx.x >= off) ? s[threadIdx.x - off] : 0;
        __syncthreads();
        s[threadIdx.x] += t;
        __syncthreads();
    }
    if (i < N_NODES) rp[i + 1] = s[threadIdx.x];
    if (threadIdx.x == 255) bsum[blockIdx.x] = s[255];
    if (i == 0) rp[0] = 0;
}

__global__ __launch_bounds__(256) void scan23_kernel(
    int* __restrict__ rp, const int* __restrict__ bsum, int nb)
{
    __shared__ int bl[256];
    int tid = threadIdx.x;
    bl[tid] = (tid < nb && tid < (int)blockIdx.x) ? bsum[tid] : 0;
    __syncthreads();
    #pragma unroll
    for (int off = 128; off; off >>= 1) {
        if (tid < off) bl[tid] += bl[tid + off];
        __syncthreads();
    }
    int pre = bl[0];
    int i = blockIdx.x * 256 + tid;
    if (i < N_NODES) rp[i + 1] += pre;
}

__global__ __launch_bounds__(256) void csr_scatter_kernel(
    const int* __restrict__ ei, const int* __restrict__ etype,
    const int* __restrict__ rp, int* __restrict__ cursor, int* __restrict__ skey)
{
    int i = blockIdx.x * 256 + threadIdx.x;
    if (i >= N_EDGES) return;
    int dst = ei[N_EDGES + i];
    int pos = rp[dst] + atomicAdd(&cursor[dst], 1);
    skey[pos] = (ei[i] << 1) | (etype[i] & 1);
}

// ---------------------------------------------------------------------------
// node_agg v3b: wave per node; Phase A lanes-parallel scalar max;
// Phase B half-wave per edge with bf16 hall gathers (8B/lane).
// ---------------------------------------------------------------------------
__global__ __launch_bounds__(256) void node_agg_kernel(
    const int* __restrict__ rp, const int* __restrict__ skey,
    const unsigned short* __restrict__ hall,
    const float* __restrict__ sL, const float* __restrict__ sR,
    float* __restrict__ out)
{
    const int lane = threadIdx.x & 63;
    const int node = (blockIdx.x * 256 + threadIdx.x) >> 6;
    if (node >= N_NODES) return;
    const int r0 = rp[node], r1 = rp[node + 1];
    if (r0 == r1) return;                 // out keeps root contribution

    const float sR0 = sR[(size_t)node * 2 + 0];
    const float sR1 = sR[(size_t)node * 2 + 1];
    const float NINF = -__builtin_inff();

    // Phase A: segment max (lanes parallel over edges)
    float mloc = NINF;
    for (int j = r0 + lane; j < r1; j += 64) {
        int key = skey[j], t = key & 1;
        float e = sL[(size_t)(key >> 1) * 2 + t] + (t ? sR1 : sR0);
        e = (e > 0.f) ? e : NEG_SLOPE * e;
        mloc = fmaxf(mloc, e);
    }
    #pragma unroll
    for (int off = 32; off; off >>= 1) mloc = fmaxf(mloc, __shfl_xor(mloc, off));

    // Phase B: half-wave per edge, 2 edges per half per iteration
    const int sl = lane & 31;
    const int half = lane >> 5;
    float denom = 0.f;
    float4 acc = make_float4(0.f, 0.f, 0.f, 0.f);

    for (int j = r0 + half; j < r1; j += 4) {
        const int j2 = j + 2;
        const bool v2 = j2 < r1;
        const int k1 = skey[j];
        const int k2 = skey[v2 ? j2 : j];
        const int t1 = k1 & 1, t2 = k2 & 1;

        float e1 = sL[(size_t)(k1 >> 1) * 2 + t1] + (t1 ? sR1 : sR0);
        float e2 = sL[(size_t)(k2 >> 1) * 2 + t2] + (t2 ? sR1 : sR0);
        e1 = (e1 > 0.f) ? e1 : NEG_SLOPE * e1;
        e2 = (e2 > 0.f) ? e2 : NEG_SLOPE * e2;
        const float w1 = __expf(e1 - mloc);
        const float w2 = v2 ? __expf(e2 - mloc) : 0.f;

        const ushort4 u1 = *(const ushort4*)&hall[((size_t)(k1 >> 1) * 2 + t1) * 128 + sl * 4];
        const ushort4 u2 = *(const ushort4*)&hall[((size_t)(k2 >> 1) * 2 + t2) * 128 + sl * 4];
        const float4 h1 = bf4_to_f4(u1);
        const float4 h2 = bf4_to_f4(u2);

        denom += w1 + w2;
        acc.x += w1 * h1.x + w2 * h2.x;
        acc.y += w1 * h1.y + w2 * h2.y;
        acc.z += w1 * h1.z + w2 * h2.z;
        acc.w += w1 * h1.w + w2 * h2.w;
    }

    // merge the two halves (lane i <-> i+32 hold same channels)
    denom += __shfl_xor(denom, 32);
    acc.x += __shfl_xor(acc.x, 32);
    acc.y += __shfl_xor(acc.y, 32);
    acc.z += __shfl_xor(acc.z, 32);
    acc.w += __shfl_xor(acc.w, 32);

    if (half == 0) {
        const float inv = 1.f / (denom + EPS_F);
        float4* op = (float4*)&out[(size_t)node * 128 + sl * 4];
        float4 o = *op;
        o.x += acc.x * inv;
        o.y += acc.y * inv;
        o.z += acc.z * inv;
        o.w += acc.w * inv;
        *op = o;
    }
}

// ---------------------------------------------------------------------------
extern "C" void kernel_launch(void* const* d_in, const int* in_sizes, int n_in,
                              void* d_out, int out_size, void* d_ws, size_t ws_size,
                              hipStream_t stream) {
    const float* x      = (const float*)d_in[0];
    const int*   ei     = (const int*)d_in[1];
    const int*   etype  = (const int*)d_in[2];
    const float* weight = (const float*)d_in[3];
    const float* att    = (const float*)d_in[4];
    const float* root_w = (const float*)d_in[5];
    const float* root_b = (const float*)d_in[6];
    float* out = (float*)d_out;

    // ws layout:
    unsigned short* hall = (unsigned short*)d_ws;               // 50048*2*128 bf16
    float* sL   = (float*)(hall + (size_t)N_PAD * 2 * 128);     // 50048*2
    float* sR   = sL + (size_t)N_PAD * 2;                       // 50048*2
    int* deg    = (int*)(sR + (size_t)N_PAD * 2);               // 50048
    int* cursor = deg + N_PAD;                                  // 50048
    int* rp     = cursor + N_PAD;                               // 50056
    int* bsum   = rp + 50056;                                   // 256
    int* skey   = bsum + 256;                                   // 500000
    unsigned short* xhi   = (unsigned short*)(skey + N_EDGES);  // 50048*128
    unsigned short* xlo   = xhi + (size_t)N_PAD * 128;
    unsigned short* bt_hi = xlo + (size_t)N_PAD * 128;          // 384*128
    unsigned short* bt_lo = bt_hi + 384 * 128;

    const int NB_E = (N_EDGES + 255) / 256;   // 1954
    const int NB_N = (N_NODES + 255) / 256;   // 196

    // zero deg + cursor (contiguous)
    hipMemsetAsync(deg, 0, sizeof(int) * (size_t)N_PAD * 2, stream);

    prep_kernel<<<1024, 256, 0, stream>>>(x, weight, root_w, ei,
                                          xhi, xlo, bt_hi, bt_lo, deg);

    mfma_gemm_kernel<<<3 * MBLK, 256, 0, stream>>>(
        xhi, xlo, bt_hi, bt_lo, att, root_b, hall, out, sL, sR);

    scan1_kernel<<<NB_N, 256, 0, stream>>>(deg, rp, bsum);
    scan23_kernel<<<NB_N, 256, 0, stream>>>(rp, bsum, NB_N);
    csr_scatter_kernel<<<NB_E, 256, 0, stream>>>(ei, etype, rp, cursor, skey);

    node_agg_kernel<<<(N_NODES + 3) / 4, 256, 0, stream>>>(
        rp, skey, hall, sL, sR, out);
}